// Round 2
// baseline (10.123 us; speedup 1.0000x reference)
//
#include <hip/hip_runtime.h>
#include <hip/hip_bf16.h>

// ARIMA-collapse kernel, round 2.
// Reference facts exploited:
//  - ma_term is identically zero (e_window never updated) -> w_ma unused
//  - D=1 differencing + final cumsum -> only x_enc[:, 4087:4096, :] matters
//  - per-(b,c) scalar AR(8) recursion, 96 steps, then running-sum + last value
//
// R2 changes vs R1:
//  - inner-loop critical path cut to one FMA/iter: nv = fma(a7, w7, partial)
//    where partial = tree-sum of a0..a6 terms (operands available >=2 iters
//    earlier). Reassociation safe: absmax slack 6x.
//  - block=64 -> 64 blocks across 64 CUs (was 16), spreads stores over XCDs.
//
// Shapes (hardcoded per reference): B=64, S=4096, C=64, P=8, PRED_LEN=96.
// Output: (B, 96, C) float32.

#define B 64
#define S 4096
#define C 64
#define PRED 96

__global__ __launch_bounds__(64) void arima_kernel(const float* __restrict__ x_enc,
                                                   const float* __restrict__ w_ar,
                                                   float* __restrict__ out) {
    int tid = blockIdx.x * blockDim.x + threadIdx.x;   // 0 .. B*C-1
    if (tid >= B * C) return;
    int b = tid >> 6;          // /64
    int c = tid & 63;

    const float* xb = x_enc + (size_t)b * S * C + c;

    // Load the last 9 x_enc values (independent loads, one vmcnt wait),
    // form the 8 trailing diffs: w[p] = x[4088+p] - x[4087+p].
    float x0 = xb[(size_t)4087 * C];
    float x1 = xb[(size_t)4088 * C];
    float x2 = xb[(size_t)4089 * C];
    float x3 = xb[(size_t)4090 * C];
    float x4 = xb[(size_t)4091 * C];
    float x5 = xb[(size_t)4092 * C];
    float x6 = xb[(size_t)4093 * C];
    float x7 = xb[(size_t)4094 * C];
    float x8 = xb[(size_t)4095 * C];

    float w0 = x1 - x0, w1 = x2 - x1, w2 = x3 - x2, w3 = x4 - x3;
    float w4 = x5 - x4, w5 = x6 - x5, w6 = x7 - x6, w7 = x8 - x7;

    float a0 = w_ar[0], a1 = w_ar[1], a2 = w_ar[2], a3 = w_ar[3];
    float a4 = w_ar[4], a5 = w_ar[5], a6 = w_ar[6], a7 = w_ar[7];

    float acc = x8;                       // cumsum base = x_enc[b, 4095, c]
    float* ob = out + (size_t)b * PRED * C + c;

#pragma unroll
    for (int t = 0; t < PRED; ++t) {
        // partial: tree sum of the 7 "old" taps (all available early);
        // critical path is only the final fma through w7 (= nv_{t-1}).
        float p01 = __builtin_fmaf(a0, w0, a1 * w1);
        float p23 = __builtin_fmaf(a2, w2, a3 * w3);
        float p45 = __builtin_fmaf(a4, w4, a5 * w5);
        float p06 = (p01 + p23) + __builtin_fmaf(a6, w6, p45);
        float nv  = __builtin_fmaf(a7, w7, p06);
        w0 = w1; w1 = w2; w2 = w3; w3 = w4; w4 = w5; w5 = w6; w6 = w7; w7 = nv;
        acc += nv;
        ob[(size_t)t * C] = acc;
    }
}

extern "C" void kernel_launch(void* const* d_in, const int* in_sizes, int n_in,
                              void* d_out, int out_size, void* d_ws, size_t ws_size,
                              hipStream_t stream) {
    const float* x_enc = (const float*)d_in[0];
    const float* w_ar  = (const float*)d_in[4];
    float* out = (float*)d_out;

    int total = B * C;                  // 4096 threads
    int block = 64;                     // 1 wave/block -> 64 blocks over 64 CUs
    int grid = (total + block - 1) / block;
    arima_kernel<<<grid, block, 0, stream>>>(x_enc, w_ar, out);
}